// Round 6
// baseline (181.571 us; speedup 1.0000x reference)
//
#include <hip/hip_runtime.h>

typedef __attribute__((ext_vector_type(8))) short bf16x8;
typedef __attribute__((ext_vector_type(4))) float f32x4;
typedef __attribute__((ext_vector_type(8))) unsigned short u16x8;

#define BB 32
#define NN 1024
#define MM 256
#define HH 128

__device__ __forceinline__ unsigned short f2bf(float f) {
  union { float f; unsigned int u; } c; c.f = f;
  unsigned int u = c.u + 0x7fffu + ((c.u >> 16) & 1u);  // RNE
  return (unsigned short)(u >> 16);
}

// native packed f32x2 -> bf16x2 convert (RNE, 1 instr)
__device__ __forceinline__ unsigned int cvtpk(float lo, float hi) {
  unsigned int r;
  asm("v_cvt_pk_bf16_f32 %0, %1, %2" : "=v"(r) : "v"(lo), "v"(hi));
  return r;
}

// ---------------- h transpose: h[B][N][M] f32 -> hT[B][M][N] bf16 ----------------
__global__ __launch_bounds__(256)
void k_transpose_h(const float* __restrict__ hg, unsigned short* __restrict__ hTg) {
  __shared__ unsigned short tile[64][65];
  int bid = blockIdx.x;
  int b = bid >> 6;
  int t = bid & 63;
  int k0 = (t >> 2) << 6;
  int m0 = (t & 3) << 6;
  int tt = threadIdx.x;
  {
    int r = tt >> 2;
    int cg = (tt & 3) << 4;
    const float* src = hg + (((size_t)b * NN + k0 + r) * MM + m0 + cg);
#pragma unroll
    for (int i = 0; i < 4; ++i) {
      float4 v = reinterpret_cast<const float4*>(src)[i];
      tile[r][cg + i * 4 + 0] = f2bf(v.x);
      tile[r][cg + i * 4 + 1] = f2bf(v.y);
      tile[r][cg + i * 4 + 2] = f2bf(v.z);
      tile[r][cg + i * 4 + 3] = f2bf(v.w);
    }
  }
  __syncthreads();
  {
    int mr = tt >> 2;
    int kc = (tt & 3) << 4;
    alignas(16) unsigned short tmp[16];
#pragma unroll
    for (int i = 0; i < 16; ++i) tmp[i] = tile[kc + i][mr];
    unsigned short* dst = hTg + (((size_t)b * MM + m0 + mr) * NN + k0 + kc);
    *reinterpret_cast<u16x8*>(dst)     = *reinterpret_cast<u16x8*>(tmp);
    *reinterpret_cast<u16x8*>(dst + 8) = *reinterpret_cast<u16x8*>(tmp + 8);
  }
}

// ------------- W transposes -------------
__global__ __launch_bounds__(256)
void k_transpose_w(const float* __restrict__ W1, const float* __restrict__ W2,
                   unsigned short* __restrict__ W1T, unsigned short* __restrict__ W2T) {
  int idx = blockIdx.x * 256 + threadIdx.x;
  if (idx < MM * HH) {
    int hc = idx >> 8;
    int m  = idx & 255;
    W1T[idx] = f2bf(W1[m * HH + hc]);
  } else {
    int j = idx - MM * HH;
    int m  = j >> 7;
    int hd = j & 127;
    W2T[j] = f2bf(W2[hd * MM + m]);
  }
}

// ---------------- fused main ----------------
// 512 blocks x 256 threads (4 waves, 2x2: wr row-half, wc col-half).
// Block tile 64 rows x 256 cols. Phase 1 has NO LDS and NO barriers:
// A and hT MFMA fragments are loaded directly from global (L2/L3-resident;
// entire working set < 256 MB Infinity Cache). fp32->bf16 via native
// v_cvt_pk_bf16_f32. LDS only for the k-tile handoff (32 KB) -> 3 blocks/CU.
#define KLD 0
#define CLD 0   // Cld overwrites Kld after GEMM1 (Kld dead by then)

__global__ __launch_bounds__(256, 3)
void k_fused(const float* __restrict__ Ag, const float* __restrict__ hg,
             const unsigned short* __restrict__ hTg,
             const unsigned short* __restrict__ W1Tg,
             const unsigned short* __restrict__ W2Tg,
             const float* __restrict__ b1g, const float* __restrict__ b2g,
             float* __restrict__ outg) {
  __shared__ __align__(16) char smem[32768];
  __shared__ float smax[64];

  const int tid  = threadIdx.x;
  const int lane = tid & 63;
  const int wid  = tid >> 6;       // 0..3
  const int wr   = wid >> 1;       // 0..1 row half (32 rows)
  const int wc   = wid & 1;        // 0..1 col half (128 cols)
  const int l15  = lane & 15;
  const int lg   = lane >> 4;      // 0..3

  const int bid = blockIdx.x;
  const int b   = bid & 31;        // same-batch blocks share bid%8 -> same XCD L2
  const int r0  = (bid >> 5) << 6; // 16 row-blocks of 64

  const float* Ab = Ag + ((size_t)b * NN + r0) * NN;
  const unsigned short* hTb = hTg + (size_t)b * MM * NN;

  // ---- phase 1: k = A @ h, fragments direct from global, no barriers ----
  f32x4 acc[2][8];
#pragma unroll
  for (int m = 0; m < 2; ++m)
#pragma unroll
    for (int n = 0; n < 8; ++n) acc[m][n] = f32x4{0.f, 0.f, 0.f, 0.f};
  float pm[2] = {-1e30f, -1e30f};

  const float* ap[2];
#pragma unroll
  for (int m = 0; m < 2; ++m)
    ap[m] = Ab + (size_t)((wr << 5) + (m << 4) + l15) * NN + (lg << 3);
  const unsigned short* hp[8];
#pragma unroll
  for (int n = 0; n < 8; ++n)
    hp[n] = hTb + (size_t)((wc << 7) + (n << 4) + l15) * NN + (lg << 3);

#pragma unroll
  for (int kq = 0; kq < 32; ++kq) {
    const int ko = kq << 5;   // k offset, 32 per step
    bf16x8 af[2];
#pragma unroll
    for (int m = 0; m < 2; ++m) {
      float4 lo = *reinterpret_cast<const float4*>(ap[m] + ko);
      float4 hi = *reinterpret_cast<const float4*>(ap[m] + ko + 4);
      pm[m] = fmaxf(pm[m],
          fmaxf(fmaxf(fmaxf(lo.x, lo.y), fmaxf(lo.z, lo.w)),
                fmaxf(fmaxf(hi.x, hi.y), fmaxf(hi.z, hi.w))));
      uint4 q = make_uint4(cvtpk(lo.x, lo.y), cvtpk(lo.z, lo.w),
                           cvtpk(hi.x, hi.y), cvtpk(hi.z, hi.w));
      af[m] = *reinterpret_cast<bf16x8*>(&q);
    }
    bf16x8 bh[8];
#pragma unroll
    for (int n = 0; n < 8; ++n)
      bh[n] = *reinterpret_cast<const bf16x8*>(hp[n] + ko);
#pragma unroll
    for (int m = 0; m < 2; ++m)
#pragma unroll
      for (int n = 0; n < 8; ++n)
        acc[m][n] = __builtin_amdgcn_mfma_f32_16x16x32_bf16(af[m], bh[n], acc[m][n], 0, 0, 0);
  }

  // ---- rowmax finalize (reduce over lg via shfl; wc-waves hold duplicates) ----
#pragma unroll
  for (int m = 0; m < 2; ++m) {
    float v = pm[m];
    v = fmaxf(v, __shfl_xor(v, 16));
    v = fmaxf(v, __shfl_xor(v, 32));
    if (wc == 0 && lg == 0) smax[(wr << 5) + (m << 4) + l15] = v;
  }
  __syncthreads();

  // ---- write k tile (/3, bf16) -> Kld [64][512B] XOR-swizzled ----
  {
    const float inv3 = 1.0f / 3.0f;
#pragma unroll
    for (int m = 0; m < 2; ++m)
#pragma unroll
      for (int n = 0; n < 8; ++n) {
        int col = (wc << 7) + (n << 4) + l15;
#pragma unroll
        for (int j = 0; j < 4; ++j) {
          int row = (wr << 5) + (m << 4) + (lg << 2) + j;
          *reinterpret_cast<unsigned short*>(smem + KLD + row * 512 +
                                             ((col * 2) ^ ((row & 7) << 4))) =
              f2bf(acc[m][n][j] * inv3);
        }
      }
  }
  __syncthreads();

  // ---- GEMM1: y[64][128] = k @ W1 (W1T fragments straight from L2) ----
  f32x4 acc1[2][4];
#pragma unroll
  for (int m = 0; m < 2; ++m)
#pragma unroll
    for (int n = 0; n < 4; ++n) acc1[m][n] = f32x4{0.f, 0.f, 0.f, 0.f};
#pragma unroll
  for (int kq = 0; kq < 8; ++kq) {
    bf16x8 af[2], bw[4];
#pragma unroll
    for (int m = 0; m < 2; ++m) {
      int row = (wr << 5) + (m << 4) + l15;
      af[m] = *reinterpret_cast<const bf16x8*>(smem + KLD + row * 512 +
              (((kq << 6) + (lg << 4)) ^ ((row & 7) << 4)));
    }
#pragma unroll
    for (int n = 0; n < 4; ++n) {
      int col = (wc << 6) + (n << 4) + l15;
      bw[n] = *reinterpret_cast<const bf16x8*>(W1Tg + (size_t)col * 256 +
                                               (kq << 5) + (lg << 3));
    }
#pragma unroll
    for (int m = 0; m < 2; ++m)
#pragma unroll
      for (int n = 0; n < 4; ++n)
        acc1[m][n] = __builtin_amdgcn_mfma_f32_16x16x32_bf16(af[m], bw[n], acc1[m][n], 0, 0, 0);
  }
  __syncthreads();  // all waves done reading Kld; Cld may overwrite

  // ---- c = relu(y+b1) -> Cld [64][256B] XOR (aliases Kld space) ----
  {
#pragma unroll
    for (int n = 0; n < 4; ++n) {
      int col = (wc << 6) + (n << 4) + l15;
      float bias = b1g[col];
#pragma unroll
      for (int m = 0; m < 2; ++m)
#pragma unroll
        for (int j = 0; j < 4; ++j) {
          int row = (wr << 5) + (m << 4) + (lg << 2) + j;
          float v = fmaxf(acc1[m][n][j] + bias, 0.f);
          *reinterpret_cast<unsigned short*>(smem + CLD + row * 256 +
                                             ((col * 2) ^ ((row & 7) << 4))) = f2bf(v);
        }
    }
  }
  __syncthreads();

  // ---- GEMM2: out2[64][256] = c @ W2 (W2T fragments from L2) ----
  f32x4 acc2[2][8];
#pragma unroll
  for (int m = 0; m < 2; ++m)
#pragma unroll
    for (int n = 0; n < 8; ++n) acc2[m][n] = f32x4{0.f, 0.f, 0.f, 0.f};
#pragma unroll
  for (int kq = 0; kq < 4; ++kq) {
    bf16x8 af[2], bw[8];
#pragma unroll
    for (int m = 0; m < 2; ++m) {
      int row = (wr << 5) + (m << 4) + l15;
      af[m] = *reinterpret_cast<const bf16x8*>(smem + CLD + row * 256 +
              (((kq << 6) + (lg << 4)) ^ ((row & 7) << 4)));
    }
#pragma unroll
    for (int n = 0; n < 8; ++n) {
      int col = (wc << 7) + (n << 4) + l15;
      bw[n] = *reinterpret_cast<const bf16x8*>(W2Tg + (size_t)col * 128 +
                                               (kq << 5) + (lg << 3));
    }
#pragma unroll
    for (int m = 0; m < 2; ++m)
#pragma unroll
      for (int n = 0; n < 8; ++n)
        acc2[m][n] = __builtin_amdgcn_mfma_f32_16x16x32_bf16(af[m], bw[n], acc2[m][n], 0, 0, 0);
  }

  // ---- epilogue: out = (out2+b2)*mask + h*(1-mask) ----
  {
#pragma unroll
    for (int n = 0; n < 8; ++n) {
      int col = (wc << 7) + (n << 4) + l15;
      float b2v = b2g[col];
#pragma unroll
      for (int m = 0; m < 2; ++m)
#pragma unroll
        for (int j = 0; j < 4; ++j) {
          int row = (wr << 5) + (m << 4) + (lg << 2) + j;
          float kv = acc2[m][n][j] + b2v;
          float mask = smax[row];
          size_t gidx = ((size_t)b * NN + r0 + row) * MM + col;
          float hv = hg[gidx];
          outg[gidx] = kv * mask + hv * (1.f - mask);
        }
    }
  }
}

extern "C" void kernel_launch(void* const* d_in, const int* in_sizes, int n_in,
                              void* d_out, int out_size, void* d_ws, size_t ws_size,
                              hipStream_t stream) {
  (void)in_sizes; (void)n_in; (void)out_size; (void)ws_size;
  const float* A  = (const float*)d_in[0];
  const float* h  = (const float*)d_in[1];
  const float* W1 = (const float*)d_in[2];
  const float* b1 = (const float*)d_in[3];
  const float* W2 = (const float*)d_in[4];
  const float* b2 = (const float*)d_in[5];
  float* out = (float*)d_out;

  unsigned short* hT  = (unsigned short*)d_ws;
  unsigned short* W1T = (unsigned short*)((char*)d_ws + (size_t)BB * MM * NN * 2);
  unsigned short* W2T = W1T + MM * HH;

  k_transpose_h<<<BB * 64, 256, 0, stream>>>(h, hT);
  k_transpose_w<<<256, 256, 0, stream>>>(W1, W2, W1T, W2T);
  k_fused<<<BB * 16, 256, 0, stream>>>(A, h, hT, W1T, W2T, b1, b2, out);
}

// Round 7
// 69.355 us; speedup vs baseline: 2.6180x; 2.6180x over previous
//
#include <hip/hip_runtime.h>

typedef __attribute__((ext_vector_type(8))) short bf16x8;
typedef __attribute__((ext_vector_type(4))) float f32x4;
typedef __attribute__((ext_vector_type(8))) unsigned short u16x8;

#define BB 32
#define NN 1024
#define MM 256
#define HH 128

__device__ __forceinline__ unsigned short f2bf(float f) {
  union { float f; unsigned int u; } c; c.f = f;
  unsigned int u = c.u + 0x7fffu + ((c.u >> 16) & 1u);  // RNE
  return (unsigned short)(u >> 16);
}

// native packed f32x2 -> bf16x2 (RNE, 1 instr) — verified absmax 0.125 in r6
__device__ __forceinline__ unsigned int cvtpk(float lo, float hi) {
  unsigned int r;
  asm("v_cvt_pk_bf16_f32 %0, %1, %2" : "=v"(r) : "v"(lo), "v"(hi));
  return r;
}

// volatile global load: CANNOT be sunk past the explicit vmcnt wait
__device__ __forceinline__ float4 gload_f4(const float* p) {
  float4 r;
  asm volatile("global_load_dwordx4 %0, %1, off" : "=v"(r) : "v"(p) : "memory");
  return r;
}

typedef __attribute__((address_space(3))) unsigned int as3_u32;
typedef const __attribute__((address_space(1))) unsigned int as1_u32;
__device__ __forceinline__ void gl_lds16(const void* g, void* l) {
  __builtin_amdgcn_global_load_lds((as1_u32*)g, (as3_u32*)l, 16, 0, 0);
}

// ---------------- h transpose: h[B][N][M] f32 -> hT[B][M][N] bf16 ----------------
__global__ __launch_bounds__(256)
void k_transpose_h(const float* __restrict__ hg, unsigned short* __restrict__ hTg) {
  __shared__ unsigned short tile[64][65];
  int bid = blockIdx.x;
  int b = bid >> 6;
  int t = bid & 63;
  int k0 = (t >> 2) << 6;
  int m0 = (t & 3) << 6;
  int tt = threadIdx.x;
  {
    int r = tt >> 2;
    int cg = (tt & 3) << 4;
    const float* src = hg + (((size_t)b * NN + k0 + r) * MM + m0 + cg);
#pragma unroll
    for (int i = 0; i < 4; ++i) {
      float4 v = reinterpret_cast<const float4*>(src)[i];
      tile[r][cg + i * 4 + 0] = f2bf(v.x);
      tile[r][cg + i * 4 + 1] = f2bf(v.y);
      tile[r][cg + i * 4 + 2] = f2bf(v.z);
      tile[r][cg + i * 4 + 3] = f2bf(v.w);
    }
  }
  __syncthreads();
  {
    int mr = tt >> 2;
    int kc = (tt & 3) << 4;
    alignas(16) unsigned short tmp[16];
#pragma unroll
    for (int i = 0; i < 16; ++i) tmp[i] = tile[kc + i][mr];
    unsigned short* dst = hTg + (((size_t)b * MM + m0 + mr) * NN + k0 + kc);
    *reinterpret_cast<u16x8*>(dst)     = *reinterpret_cast<u16x8*>(tmp);
    *reinterpret_cast<u16x8*>(dst + 8) = *reinterpret_cast<u16x8*>(tmp + 8);
  }
}

// ------------- W transposes -------------
__global__ __launch_bounds__(256)
void k_transpose_w(const float* __restrict__ W1, const float* __restrict__ W2,
                   unsigned short* __restrict__ W1T, unsigned short* __restrict__ W2T) {
  int idx = blockIdx.x * 256 + threadIdx.x;
  if (idx < MM * HH) {
    int hc = idx >> 8;
    int m  = idx & 255;
    W1T[idx] = f2bf(W1[m * HH + hc]);
  } else {
    int j = idx - MM * HH;
    int m  = j >> 7;
    int hd = j & 127;
    W2T[j] = f2bf(W2[hd * MM + m]);
  }
}

// ---------------- fused main ----------------
// 256 blocks x 512 threads (8 waves 2x4). Block tile 128 rows x 256 cols.
// Phase 1 (k = A@h), 16 K-steps of 64, ONE lgkm-barrier per step:
//   step t: [issue A(t+1) via volatile asm regs + H(t+1) via global_load_lds]
//           CONSUME(t)  (bf16 frags from LDS, 32 MFMA)
//           vmcnt(0)  (A regs + H LDS landed; issued a full consume ago)
//           cvt A(t+1)->bf16 + rowmax -> ds_write A_bf[(t+1)&1]
//           lgkmcnt(0); s_barrier
// Writes always target the buffer whose readers retired at the PREVIOUS
// barrier (dbuf parity), so one barrier per step is sufficient.
// LDS: A0@0 A1@16K H0@32K H1@64K (96K); phase2 alias Kld@0(64K) Cld@64K(32K).
#define AB0 0
#define AB1 16384
#define HB0 32768
#define HB1 65536
#define KLD 0
#define CLD 65536

#define PIPE_BARRIER() do { \
  asm volatile("s_waitcnt lgkmcnt(0)" ::: "memory"); \
  __builtin_amdgcn_s_barrier(); \
  asm volatile("" ::: "memory"); } while (0)

#define VMWAIT0() do { \
  asm volatile("s_waitcnt vmcnt(0)" ::: "memory"); \
  __builtin_amdgcn_sched_barrier(0); } while (0)

__global__ __launch_bounds__(512, 1)
void k_fused(const float* __restrict__ Ag, const float* __restrict__ hg,
             const unsigned short* __restrict__ hTg,
             const unsigned short* __restrict__ W1Tg,
             const unsigned short* __restrict__ W2Tg,
             const float* __restrict__ b1g, const float* __restrict__ b2g,
             float* __restrict__ outg) {
  __shared__ __align__(16) char smem[98304];
  __shared__ float smax[128];

  const int tid  = threadIdx.x;
  const int lane = tid & 63;
  const int wid  = tid >> 6;       // 0..7
  const int wr   = wid >> 2;       // 0..1 (row half)
  const int wc   = wid & 3;        // 0..3 (col quarter)
  const int l15  = lane & 15;
  const int lg   = lane >> 4;      // 0..3

  const int bid = blockIdx.x;
  const int b   = bid & 31;        // same-batch blocks share bid%8 -> same XCD
  const int r0  = (bid >> 5) << 7; // 8 row-blocks of 128

  const float* Ab = Ag + ((size_t)b * NN + r0) * NN;
  const unsigned short* hTb = hTg + (size_t)b * MM * NN;

  // ---- A staging geometry (round-1 verified): thread -> (row, 16-float col) ----
  const int arow = tid >> 2;          // 0..127
  const int acg  = (tid & 3) << 4;    // float col 0,16,32,48
  const int asw  = (arow & 7) << 4;
  const float* Asrc = Ab + (size_t)arow * NN + acg;

  // ---- H staging sources (round-5 verified): pre-swizzled global, linear LDS ----
  const unsigned short* baseH[4];
#pragma unroll
  for (int i = 0; i < 4; ++i) {
    int c = i * 512 + tid;           // 16B chunk id: [256 cols][8 chunks]
    int col = c >> 3, cic = c & 7;
    baseH[i] = hTb + (size_t)col * NN + ((cic ^ (col & 7)) << 3);
  }
  const int ldsW = wid << 10;        // wave-uniform base (64 lanes x 16B)

#define STAGE_H(K0, HB)                                                     \
  do {                                                                      \
    _Pragma("unroll")                                                       \
    for (int i = 0; i < 4; ++i)                                             \
      gl_lds16(baseH[i] + (K0), smem + (HB) + ldsW + i * 8192);             \
  } while (0)

  float4 rA[4];
#define ISSUE_A(K0)                                                         \
  do {                                                                      \
    _Pragma("unroll")                                                       \
    for (int i = 0; i < 4; ++i) rA[i] = gload_f4(Asrc + (K0) + i * 4);      \
  } while (0)

  float pmax = -1e30f;
#define CVTWR(AB)                                                           \
  do {                                                                      \
    float m0 = fmaxf(fmaxf(rA[0].x, rA[0].y), fmaxf(rA[0].z, rA[0].w));     \
    float m1 = fmaxf(fmaxf(rA[1].x, rA[1].y), fmaxf(rA[1].z, rA[1].w));     \
    float m2 = fmaxf(fmaxf(rA[2].x, rA[2].y), fmaxf(rA[2].z, rA[2].w));     \
    float m3 = fmaxf(fmaxf(rA[3].x, rA[3].y), fmaxf(rA[3].z, rA[3].w));     \
    pmax = fmaxf(pmax, fmaxf(fmaxf(m0, m1), fmaxf(m2, m3)));                \
    uint4 q0 = make_uint4(cvtpk(rA[0].x, rA[0].y), cvtpk(rA[0].z, rA[0].w), \
                          cvtpk(rA[1].x, rA[1].y), cvtpk(rA[1].z, rA[1].w));\
    uint4 q1 = make_uint4(cvtpk(rA[2].x, rA[2].y), cvtpk(rA[2].z, rA[2].w), \
                          cvtpk(rA[3].x, rA[3].y), cvtpk(rA[3].z, rA[3].w));\
    *reinterpret_cast<uint4*>(smem + (AB) + arow * 128 + ((acg * 2) ^ asw)) = q0; \
    *reinterpret_cast<uint4*>(smem + (AB) + arow * 128 + ((acg * 2 + 16) ^ asw)) = q1; \
  } while (0)

  f32x4 acc[4][4];
#pragma unroll
  for (int m = 0; m < 4; ++m)
#pragma unroll
    for (int n = 0; n < 4; ++n) acc[m][n] = f32x4{0.f, 0.f, 0.f, 0.f};

#define CONSUME(AB, HB)                                                     \
  do {                                                                      \
    _Pragma("unroll")                                                       \
    for (int kk = 0; kk < 2; ++kk) {                                        \
      const int kb = (kk * 32 + (lg << 3)) * 2;                             \
      bf16x8 af[4], bh[4];                                                  \
      _Pragma("unroll")                                                     \
      for (int m = 0; m < 4; ++m) {                                         \
        int row = (wr << 6) + (m << 4) + l15;                               \
        af[m] = *reinterpret_cast<const bf16x8*>(                           \
            smem + (AB) + row * 128 + (kb ^ ((row & 7) << 4)));             \
      }                                                                     \
      _Pragma("unroll")                                                     \
      for (int n = 0; n < 4; ++n) {                                         \
        int col = (wc << 6) + (n << 4) + l15;                               \
        bh[n] = *reinterpret_cast<const bf16x8*>(                           \
            smem + (HB) + col * 128 + (kb ^ ((col & 7) << 4)));             \
      }                                                                     \
      _Pragma("unroll")                                                     \
      for (int m = 0; m < 4; ++m)                                           \
        _Pragma("unroll")                                                   \
        for (int n = 0; n < 4; ++n)                                         \
          acc[m][n] = __builtin_amdgcn_mfma_f32_16x16x32_bf16(af[m], bh[n], \
                                                              acc[m][n], 0, 0, 0); \
    }                                                                       \
  } while (0)

  // ---- prologue: step 0 staged, barrier ----
  ISSUE_A(0);
  STAGE_H(0, HB0);
  VMWAIT0();
  CVTWR(AB0);
  PIPE_BARRIER();

  // ---- phase 1: 16 K-steps ----
#pragma unroll
  for (int t = 0; t < 16; ++t) {
    if (t < 15) {
      ISSUE_A((t + 1) * 64);
      STAGE_H((t + 1) * 64, (t & 1) ? HB0 : HB1);
    }
    if (t & 1) CONSUME(AB1, HB1);
    else       CONSUME(AB0, HB0);
    if (t < 15) {
      VMWAIT0();
      if (t & 1) CVTWR(AB0);
      else       CVTWR(AB1);
      PIPE_BARRIER();
    }
  }

  // ---- rowmax finalize (4 staging lanes per row are adjacent) ----
  {
    float v = pmax;
    v = fmaxf(v, __shfl_xor(v, 1));
    v = fmaxf(v, __shfl_xor(v, 2));
    if ((tid & 3) == 0) smax[arow] = v;
  }
  __syncthreads();   // phase-1 LDS fully retired before aliasing

  // ---- write k tile (/3, bf16) -> Kld [128][512B] XOR ----
  {
    const float inv3 = 1.0f / 3.0f;
#pragma unroll
    for (int m = 0; m < 4; ++m)
#pragma unroll
      for (int n = 0; n < 4; ++n) {
        int col = (wc << 6) + (n << 4) + l15;
#pragma unroll
        for (int j = 0; j < 4; ++j) {
          int row = (wr << 6) + (m << 4) + (lg << 2) + j;
          *reinterpret_cast<unsigned short*>(smem + KLD + row * 512 +
                                             ((col * 2) ^ ((row & 7) << 4))) =
              f2bf(acc[m][n][j] * inv3);
        }
      }
  }
  __syncthreads();

  // ---- GEMM1: y[128][128] = k @ W1 (W1T fragments straight from L2) ----
  f32x4 acc1[4][2];
#pragma unroll
  for (int m = 0; m < 4; ++m)
#pragma unroll
    for (int n = 0; n < 2; ++n) acc1[m][n] = f32x4{0.f, 0.f, 0.f, 0.f};
  const int wcol1 = wc << 5;  // 0,32,64,96
#pragma unroll
  for (int kq = 0; kq < 8; ++kq) {
    bf16x8 af[4], bw[2];
#pragma unroll
    for (int m = 0; m < 4; ++m) {
      int row = (wr << 6) + (m << 4) + l15;
      af[m] = *reinterpret_cast<const bf16x8*>(smem + KLD + row * 512 +
              (((kq * 32 + (lg << 3)) * 2) ^ ((row & 7) << 4)));
    }
#pragma unroll
    for (int n = 0; n < 2; ++n) {
      int col = wcol1 + (n << 4) + l15;
      bw[n] = *reinterpret_cast<const bf16x8*>(W1Tg + (size_t)col * 256 +
                                               kq * 32 + (lg << 3));
    }
#pragma unroll
    for (int m = 0; m < 4; ++m)
#pragma unroll
      for (int n = 0; n < 2; ++n)
        acc1[m][n] = __builtin_amdgcn_mfma_f32_16x16x32_bf16(af[m], bw[n], acc1[m][n], 0, 0, 0);
  }

  // ---- c = relu(y+b1) -> Cld [128][256B] XOR (disjoint from Kld) ----
  {
#pragma unroll
    for (int n = 0; n < 2; ++n) {
      int col = wcol1 + (n << 4) + l15;
      float bias = b1g[col];
#pragma unroll
      for (int m = 0; m < 4; ++m)
#pragma unroll
        for (int j = 0; j < 4; ++j) {
          int row = (wr << 6) + (m << 4) + (lg << 2) + j;
          float v = fmaxf(acc1[m][n][j] + bias, 0.f);
          *reinterpret_cast<unsigned short*>(smem + CLD + row * 256 +
                                             ((col * 2) ^ ((row & 7) << 4))) = f2bf(v);
        }
    }
  }
  __syncthreads();

  // ---- GEMM2: out2[128][256] = c @ W2 (W2T fragments from L2) ----
  f32x4 acc2[4][4];
#pragma unroll
  for (int m = 0; m < 4; ++m)
#pragma unroll
    for (int n = 0; n < 4; ++n) acc2[m][n] = f32x4{0.f, 0.f, 0.f, 0.f};
#pragma unroll
  for (int kq = 0; kq < 4; ++kq) {
    bf16x8 af[4], bw[4];
#pragma unroll
    for (int m = 0; m < 4; ++m) {
      int row = (wr << 6) + (m << 4) + l15;
      af[m] = *reinterpret_cast<const bf16x8*>(smem + CLD + row * 256 +
              (((kq * 32 + (lg << 3)) * 2) ^ ((row & 7) << 4)));
    }
#pragma unroll
    for (int n = 0; n < 4; ++n) {
      int col = (wc << 6) + (n << 4) + l15;
      bw[n] = *reinterpret_cast<const bf16x8*>(W2Tg + (size_t)col * 128 +
                                               kq * 32 + (lg << 3));
    }
#pragma unroll
    for (int m = 0; m < 4; ++m)
#pragma unroll
      for (int n = 0; n < 4; ++n)
        acc2[m][n] = __builtin_amdgcn_mfma_f32_16x16x32_bf16(af[m], bw[n], acc2[m][n], 0, 0, 0);
  }

  // ---- epilogue: out = (out2+b2)*mask + h*(1-mask) ----
  {
#pragma unroll
    for (int n = 0; n < 4; ++n) {
      int col = (wc << 6) + (n << 4) + l15;
      float b2v = b2g[col];
#pragma unroll
      for (int m = 0; m < 4; ++m)
#pragma unroll
        for (int j = 0; j < 4; ++j) {
          int row = (wr << 6) + (m << 4) + (lg << 2) + j;
          float kv = acc2[m][n][j] + b2v;
          float mask = smax[row];
          size_t gidx = ((size_t)b * NN + r0 + row) * MM + col;
          float hv = hg[gidx];
          outg[gidx] = kv * mask + hv * (1.f - mask);
        }
    }
  }
#undef CONSUME
#undef CVTWR
#undef ISSUE_A
#undef STAGE_H
}

extern "C" void kernel_launch(void* const* d_in, const int* in_sizes, int n_in,
                              void* d_out, int out_size, void* d_ws, size_t ws_size,
                              hipStream_t stream) {
  (void)in_sizes; (void)n_in; (void)out_size; (void)ws_size;
  const float* A  = (const float*)d_in[0];
  const float* h  = (const float*)d_in[1];
  const float* W1 = (const float*)d_in[2];
  const float* b1 = (const float*)d_in[3];
  const float* W2 = (const float*)d_in[4];
  const float* b2 = (const float*)d_in[5];
  float* out = (float*)d_out;

  unsigned short* hT  = (unsigned short*)d_ws;
  unsigned short* W1T = (unsigned short*)((char*)d_ws + (size_t)BB * MM * NN * 2);
  unsigned short* W2T = W1T + MM * HH;

  k_transpose_h<<<BB * 64, 256, 0, stream>>>(h, hT);
  k_transpose_w<<<256, 256, 0, stream>>>(W1, W2, W1T, W2T);
  k_fused<<<BB * 8, 512, 0, stream>>>(A, h, hT, W1T, W2T, b1, b2, out);
}